// Round 1
// baseline (582.241 us; speedup 1.0000x reference)
//
#include <hip/hip_runtime.h>

// Linear_AB_I8_DE_F32: y[m,n] = 0.01 * sum_k x8[m,k]*w8[n,k] + bias[n]
// M=4096 (2*2048), N=11008, K=4096. Inputs are int8 values in int32 containers.
//
// Strategy (R1): pack int32->int8 into d_ws (memory-bound pass), then
// m97-structure i8 MFMA GEMM: 128x128 tile, 4 waves, 4x4 frags of
// mfma_i32_16x16x64_i8, global_load_lds width=16, BK=64 (64B rows — same
// staging geometry as the verified bf16 m97 kernel).

#define M_DIM 4096
#define N_DIM 11008
#define K_DIM 4096
#define BM 128
#define BN 128
#define BK 64
#define ALPHA 0.01f

typedef __attribute__((ext_vector_type(4))) int i32x4;

// ---------------- pack: int32 container -> int8 bytes ----------------
// each thread: 4 int32 in (16B coalesced) -> 1 packed uint out (4B coalesced)
__global__ __launch_bounds__(256) void pack_i8_kernel(
    const int4* __restrict__ in, unsigned int* __restrict__ out, int n4)
{
    int i = blockIdx.x * blockDim.x + threadIdx.x;
    if (i < n4) {
        int4 v = in[i];
        out[i] = (v.x & 0xff) | ((v.y & 0xff) << 8) |
                 ((v.z & 0xff) << 16) | ((unsigned)(v.w & 0xff) << 24);
    }
}

// ---------------- GEMM ----------------
__global__ __launch_bounds__(256) void gemm_i8_kernel(
    const char* __restrict__ A,   // [M][K] int8, row-major
    const char* __restrict__ B,   // [N][K] int8, row-major (B^T layout)
    const float* __restrict__ bias, // [N]
    float* __restrict__ C)        // [M][N] fp32
{
    __shared__ __attribute__((aligned(16))) char As[BM * BK]; // 8 KB
    __shared__ __attribute__((aligned(16))) char Bs[BN * BK]; // 8 KB

    const int tid  = threadIdx.x;
    const int lane = tid & 63;
    const int wave = tid >> 6;
    const int waveM = (wave >> 1) * 64;  // 2x2 wave grid, 64x64 per wave
    const int waveN = (wave & 1) * 64;
    const int bm = blockIdx.y * BM;
    const int bn = blockIdx.x * BN;

    const int lrow  = lane & 15;
    const int lquad = lane >> 4;

    // staging: 256 threads, 4 threads per 64B row -> 64 rows per chunk
    const int srow  = tid >> 2;
    const int scol  = (tid & 3) * 16;
    const char* Abase = A + (size_t)(bm + srow) * K_DIM + scol;
    const char* Bbase = B + (size_t)(bn + srow) * K_DIM + scol;

    i32x4 acc[4][4] = {};

    for (int k0 = 0; k0 < K_DIM; k0 += BK) {
        // global -> LDS, 16B per lane, LDS contiguous in lane order (wave-uniform base + lane*16)
        __builtin_amdgcn_global_load_lds(
            (const __attribute__((address_space(1))) void*)(Abase + k0),
            (__attribute__((address_space(3))) void*)(As + tid * 16), 16, 0, 0);
        __builtin_amdgcn_global_load_lds(
            (const __attribute__((address_space(1))) void*)(Abase + (size_t)64 * K_DIM + k0),
            (__attribute__((address_space(3))) void*)(As + 4096 + tid * 16), 16, 0, 0);
        __builtin_amdgcn_global_load_lds(
            (const __attribute__((address_space(1))) void*)(Bbase + k0),
            (__attribute__((address_space(3))) void*)(Bs + tid * 16), 16, 0, 0);
        __builtin_amdgcn_global_load_lds(
            (const __attribute__((address_space(1))) void*)(Bbase + (size_t)64 * K_DIM + k0),
            (__attribute__((address_space(3))) void*)(Bs + 4096 + tid * 16), 16, 0, 0);
        __syncthreads();

        i32x4 a[4], b[4];
#pragma unroll
        for (int i = 0; i < 4; i++)
            a[i] = *(const i32x4*)(As + (waveM + i * 16 + lrow) * BK + lquad * 16);
#pragma unroll
        for (int j = 0; j < 4; j++)
            b[j] = *(const i32x4*)(Bs + (waveN + j * 16 + lrow) * BK + lquad * 16);

#pragma unroll
        for (int i = 0; i < 4; i++)
#pragma unroll
            for (int j = 0; j < 4; j++)
                acc[i][j] = __builtin_amdgcn_mfma_i32_16x16x64_i8(a[i], b[j], acc[i][j], 0, 0, 0);

        __syncthreads();
    }

    // epilogue: C/D layout col=lane&15, row=(lane>>4)*4+reg (i8-verified)
#pragma unroll
    for (int i = 0; i < 4; i++) {
        const int r0 = bm + waveM + i * 16 + lquad * 4;
#pragma unroll
        for (int j = 0; j < 4; j++) {
            const int c0 = bn + waveN + j * 16 + lrow;
            const float bv = bias[c0];
#pragma unroll
            for (int r = 0; r < 4; r++) {
                C[(size_t)(r0 + r) * N_DIM + c0] = ALPHA * (float)acc[i][j][r] + bv;
            }
        }
    }
}

extern "C" void kernel_launch(void* const* d_in, const int* in_sizes, int n_in,
                              void* d_out, int out_size, void* d_ws, size_t ws_size,
                              hipStream_t stream) {
    const int*   x    = (const int*)d_in[0];    // [2,2048,4096] int8-in-int32
    const int*   w    = (const int*)d_in[1];    // [11008,4096]  int8-in-int32
    const float* bias = (const float*)d_in[2];  // [1,11008] fp32
    float*       out  = (float*)d_out;          // [2,2048,11008] fp32

    char* Ap = (char*)d_ws;                          // 16,777,216 B
    char* Wp = (char*)d_ws + (size_t)M_DIM * K_DIM;  // 45,088,768 B

    const int n4x = M_DIM * K_DIM / 4;   // 4,194,304  -> 16384 blocks
    const int n4w = N_DIM * K_DIM / 4;   // 11,272,192 -> 44032 blocks
    pack_i8_kernel<<<n4x / 256, 256, 0, stream>>>((const int4*)x, (unsigned int*)Ap, n4x);
    pack_i8_kernel<<<n4w / 256, 256, 0, stream>>>((const int4*)w, (unsigned int*)Wp, n4w);

    dim3 grid(N_DIM / BN, M_DIM / BM);  // (86, 32)
    gemm_i8_kernel<<<grid, 256, 0, stream>>>(Ap, Wp, bias, out);
}